// Round 3
// baseline (163.449 us; speedup 1.0000x reference)
//
#include <hip/hip_runtime.h>
#include <hip/hip_fp16.h>

// ---------------------------------------------------------------------------
// B=8, N=1024, F=320, H=5 (heads collapse: at = (Q·K^T)/8)
// R18: fused_attn v3 — fix R17's latency exposure.
//   R17 failed on occupancy (2 waves/SIMD) + register starvation (qreg=80
//   VGPR left no pipelining headroom; VGPR_Count=80 total). v3:
//   - 1024 threads (16 waves, 4/SIMD), 256 blocks (same L2-reuse footprint).
//   - No qreg: Q A-frags loaded per-kc straight from L2 (2 extra 16B loads
//     per kc; Q is L2-resident). VGPR demand ~90 -> fits 128 cap, compiler
//     can prefetch ahead.
//   - Per wave: phase A owns 64 at-cols (acc[4][2]); phase C owns 16 rows x
//     80 cols x one k-half (acc[5]).
//   - Phase B radix topk is wave-private (hist[wave]) -> NO __syncthreads
//     inside; only 4 block barriers in the whole kernel.
//   Numerics: identical fragment addresses + k-ascending chains as R17
//   (passed, absmax 0.03125) -> bit-identical.
// Pipeline: prep_all -> g1_combined (hWT + Q/K) -> fused_attn.
// ---------------------------------------------------------------------------

typedef __attribute__((ext_vector_type(8))) _Float16 half8;
typedef __attribute__((ext_vector_type(4))) float f32x4;

// ---- stage a (nrow16*16) x 32 fp16 tile into LDS, K-chunk XOR-swizzled -----
// (used by g1_combined only)
__device__ __forceinline__ void stage_tile(const __half* g, __half* lds,
                                           int nrow16, int ld, int wave, int lane) {
    const int r = lane >> 2;
    const int c = ((lane & 3) ^ ((lane >> 3) & 3)) * 8;  // swizzled chunk
    for (int i = wave; i < nrow16; i += 4) {
        const __half* src = g + (long)(i * 16 + r) * ld + c;
        __builtin_amdgcn_global_load_lds(
            (const __attribute__((address_space(1))) unsigned int*)src,
            (__attribute__((address_space(3))) unsigned int*)(lds + i * 512),
            16, 0, 0);
    }
}

// ---------------------------------------------------------------------------
// 128x128 NT fp16 dbuf GEMM body, CH=2 (BK=64), runtime bx/by. K=320 -> 5
// barrier rounds. Buffer: [A c0][A c1][B c0][B c1], 4096 halfs each.
// EPI 1: +bqk, deinterleave -> Q,K fp16.  EPI 2: fp16 store (hWT, ldc=8192).
// ---------------------------------------------------------------------------
template <int EPI>
__device__ __forceinline__ void gemm_body(
    const __half* __restrict__ A, const __half* __restrict__ B,
    void* __restrict__ C, void* __restrict__ C2, const float* __restrict__ bias,
    int lda, int ldb, int ldc, int bx, int by, __half* smem)
{
    constexpr int BUF = 16384;  // (4096+4096)*2 halfs
    const int tid  = threadIdx.x;
    const int lane = tid & 63;
    const int wave = tid >> 6;
    const int wm   = wave >> 1;
    const int wn   = wave & 1;

    const __half* Ab = A + (long)by * 128 * lda;
    const __half* Bb = B + (long)bx * 128 * ldb;

    f32x4 acc[4][4];
    #pragma unroll
    for (int i = 0; i < 4; ++i)
        #pragma unroll
        for (int j = 0; j < 4; ++j) acc[i][j] = (f32x4){0.f, 0.f, 0.f, 0.f};

    const int lrow = lane & 15;
    const int quad = lane >> 4;
    const int swz = (quad ^ ((lrow >> 1) & 3)) * 8;

    #pragma unroll
    for (int c = 0; c < 2; ++c) {
        stage_tile(Ab + c * 32, smem + c * 4096, 8, lda, wave, lane);
        stage_tile(Bb + c * 32, smem + 8192 + c * 4096, 8, ldb, wave, lane);
    }

    for (int it = 0; it < 5; ++it) {
        __syncthreads();
        if (it + 1 < 5) {
            __half* nb = smem + ((it + 1) & 1) * BUF;
            const int k1 = (it + 1) * 64;
            #pragma unroll
            for (int c = 0; c < 2; ++c) {
                stage_tile(Ab + k1 + c * 32, nb + c * 4096, 8, lda, wave, lane);
                stage_tile(Bb + k1 + c * 32, nb + 8192 + c * 4096, 8, ldb, wave, lane);
            }
        }
        const __half* buf = smem + (it & 1) * BUF;
        #pragma unroll
        for (int c = 0; c < 2; ++c) {
            const __half* pA = buf + c * 4096 + (wm * 64 + lrow) * 32 + swz;
            const __half* pB = buf + 8192 + c * 4096 + (wn * 64 + lrow) * 32 + swz;
            half8 ah[4], bh[4];
            #pragma unroll
            for (int mt = 0; mt < 4; ++mt) ah[mt] = *(const half8*)(pA + mt * 512);
            #pragma unroll
            for (int nt = 0; nt < 4; ++nt) bh[nt] = *(const half8*)(pB + nt * 512);
            #pragma unroll
            for (int mt = 0; mt < 4; ++mt)
                #pragma unroll
                for (int nt = 0; nt < 4; ++nt)
                    acc[mt][nt] = __builtin_amdgcn_mfma_f32_16x16x32_f16(
                        ah[mt], bh[nt], acc[mt][nt], 0, 0, 0);
        }
    }

    const int row_base = by * 128 + wm * 64;
    const int col_base = bx * 128 + wn * 64;
    #pragma unroll
    for (int mt = 0; mt < 4; ++mt)
        #pragma unroll
        for (int nt = 0; nt < 4; ++nt)
            #pragma unroll
            for (int r = 0; r < 4; ++r) {
                const int row = row_base + mt * 16 + quad * 4 + r;
                const int col = col_base + nt * 16 + lrow;
                const float v = acc[mt][nt][r];
                if (EPI == 1) {
                    const float val = v + bias[col];
                    const long idx = (long)row * 320 + (col >> 1);
                    if (col & 1) ((__half*)C2)[idx] = __float2half(val);
                    else         ((__half*)C)[idx]  = __float2half(val);
                } else {
                    ((__half*)C)[(long)row * ldc + col] = __float2half(v);
                }
            }
}

// ---- combined: blocks 0..191 do hWT (64x3 tiles); 192..511 do G1' (5x64) ---
__global__ __launch_bounds__(256) void g1_combined(
    const __half* __restrict__ h16, const __half* __restrict__ wTp,
    const __half* __restrict__ WqkT, __half* __restrict__ hWT,
    __half* __restrict__ Q, __half* __restrict__ Kb,
    const float* __restrict__ bqk)
{
    __shared__ __half smem[2 * 16384];
    const int bx = blockIdx.x;
    if (bx < 192) {
        gemm_body<2>(wTp, h16, hWT, nullptr, nullptr,
                     320, 320, 8192, bx % 64, bx / 64, smem);
    } else {
        const int b = bx - 192;
        gemm_body<1>(h16, WqkT, Q, Kb, bqk,
                     320, 320, 320, b % 5, b / 5, smem);
    }
}

// ---- fused prep: h->fp16 (blocks 0..2559) | Wqk^T | weight^T --------------
__global__ __launch_bounds__(256) void prep_all(
    const float* __restrict__ h, ushort4* __restrict__ h16,
    const float* __restrict__ Wqk, __half* __restrict__ WqkT,
    const float* __restrict__ weight, __half* __restrict__ wTp)
{
    const int bx = blockIdx.x;
    if (bx < 2560) {
        const int i = bx * 256 + threadIdx.x;
        const float4 v = ((const float4*)h)[i];
        ushort4 o;
        o.x = __half_as_ushort(__float2half(v.x));
        o.y = __half_as_ushort(__float2half(v.y));
        o.z = __half_as_ushort(__float2half(v.z));
        o.w = __half_as_ushort(__float2half(v.w));
        h16[i] = o;
        return;
    }
    __shared__ float t[32][33];
    const float* src;
    __half* dst;
    int ldS, ldT, c0, r0;
    if (bx < 2760) {
        const int b = bx - 2560;
        src = Wqk; dst = WqkT; ldS = 640; ldT = 320;
        c0 = (b % 20) * 32; r0 = (b / 20) * 32;
    } else {
        const int b = bx - 2760;
        src = weight; dst = wTp; ldS = 320; ldT = 320;
        c0 = (b % 10) * 32; r0 = (b / 10) * 32;
    }
    const int lx = threadIdx.x & 31, ly = threadIdx.x >> 5;
    #pragma unroll
    for (int i = 0; i < 4; ++i)
        t[ly + 8 * i][lx] = src[(long)(r0 + ly + 8 * i) * ldS + c0 + lx];
    __syncthreads();
    #pragma unroll
    for (int i = 0; i < 4; ++i)
        dst[(long)(c0 + ly + 8 * i) * ldT + r0 + lx] = __float2half(t[lx][ly + 8 * i]);
}

// ---------------------------------------------------------------------------
// fused_attn v3: per block = 32 query rows of one batch (batch = bid&7).
// 1024 threads = 16 waves (4/SIMD). Grid 256 = 1 block/CU.
// Phase A: P = 0.125 * Q_rows @ K_b^T. Wave w owns cols [w*64, w*64+64).
//   A-frags (Q) and B-frags (K) loaded per-lane straight from L2 (16B,
//   full-line coalesced). No LDS staging, no barriers, acc[4][2].
// Phase B: exact 171st-largest per row (2-pass radix) + softmax; hist is
//   wave-private -> no block syncs. 2 rows per wave.
// Phase C: out = attn @ hW_b + bias. Wave -> (q4 = w&3: 80 cols,
//   mi2 = (w>>2)&1: 16 rows, kh = w>>3: k-half). acc[5]; f32 reduction
//   aliases P after its final read.
// LDS: P 64 KB + hist 16 KB = 80 KB. 4 block barriers total.
// ---------------------------------------------------------------------------
__global__ __launch_bounds__(1024, 4) void fused_attn(
    const __half* __restrict__ Q, const __half* __restrict__ Kmat,
    const __half* __restrict__ hWT, const float* __restrict__ bias,
    float* __restrict__ out)
{
    __shared__ __half P[32768];      // 32 x 1024 fp16, idx ^= (row&7)<<3
    __shared__ int hist[16][256];

    const int tid  = threadIdx.x;
    const int lane = tid & 63;
    const int wave = tid >> 6;       // 0..15
    const int lrow = lane & 15;
    const int quad = lane >> 4;

    const int b  = blockIdx.x & 7;          // batch -> XCD affinity
    const int r0 = (blockIdx.x >> 3) * 32;  // query-row base

    const __half* Qb = Q    + (long)(b * 1024 + r0) * 320;
    const __half* Kb = Kmat + (long)b * 327680;
    const __half* Wb = hWT  + (long)b * 1024;

    // ---------------- Phase A: P = 0.125 * Q @ K^T ----------------
    f32x4 acc[4][2];
    #pragma unroll
    for (int i = 0; i < 4; ++i)
        #pragma unroll
        for (int j = 0; j < 2; ++j) acc[i][j] = (f32x4){0.f, 0.f, 0.f, 0.f};

    const __half* Qf = Qb + (long)lrow * 320 + quad * 8;
    const __half* Kw = Kb + (long)(wave * 64 + lrow) * 320 + quad * 8;
    #pragma unroll
    for (int kc = 0; kc < 10; ++kc) {
        half8 ah[2], bh[4];
        #pragma unroll
        for (int mi = 0; mi < 2; ++mi)
            ah[mi] = *(const half8*)(Qf + (long)mi * 16 * 320 + kc * 32);
        #pragma unroll
        for (int cb = 0; cb < 4; ++cb)
            bh[cb] = *(const half8*)(Kw + (long)cb * 16 * 320 + kc * 32);
        #pragma unroll
        for (int cb = 0; cb < 4; ++cb)
            #pragma unroll
            for (int mi = 0; mi < 2; ++mi)
                acc[cb][mi] = __builtin_amdgcn_mfma_f32_16x16x32_f16(
                    ah[mi], bh[cb], acc[cb][mi], 0, 0, 0);
    }
    #pragma unroll
    for (int cb = 0; cb < 4; ++cb)
        #pragma unroll
        for (int mi = 0; mi < 2; ++mi)
            #pragma unroll
            for (int rr = 0; rr < 4; ++rr) {
                const int row = mi * 16 + quad * 4 + rr;
                const int col = wave * 64 + cb * 16 + lrow;
                P[((row << 10) + col) ^ ((row & 7) << 3)] =
                    __float2half(0.125f * acc[cb][mi][rr]);
            }
    __syncthreads();

    // ---------------- Phase B: topk + softmax (wave-private) ----------------
    #pragma unroll
    for (int j = 0; j < 2; ++j) {
        const int row  = wave * 2 + j;
        const int key8 = (row & 7) << 3;
        const int base = (row << 10) + lane * 16;

        unsigned short vs[16];
        *(uint4*)&vs[0] = *(const uint4*)&P[base ^ key8];
        *(uint4*)&vs[8] = *(const uint4*)&P[(base + 8) ^ key8];

        unsigned key[16];
        #pragma unroll
        for (int i = 0; i < 16; ++i) {
            const unsigned u = vs[i];
            key[i] = (u & 0x8000u) ? ((~u) & 0xFFFFu) : (u | 0x8000u);
        }

        unsigned prefix = 0, pmask = 0;
        int kk = 171;

        #pragma unroll
        for (int pass = 0; pass < 2; ++pass) {
            const int shift = 8 - 8 * pass;
            *(int4*)&hist[wave][lane * 4] = make_int4(0, 0, 0, 0);
            #pragma unroll
            for (int i = 0; i < 16; ++i) {
                if ((key[i] & pmask) == prefix)
                    atomicAdd(&hist[wave][(key[i] >> shift) & 255], 1);
            }
            const int4 hh = *(const int4*)&hist[wave][lane * 4];
            const int s = hh.x + hh.y + hh.z + hh.w;
            int suf = s;
            #pragma unroll
            for (int off = 1; off < 64; off <<= 1) {
                const int o = __shfl_down(suf, off);
                if (lane + off < 64) suf += o;
            }
            const int cgt3 = suf - s;
            const int cgt2 = cgt3 + hh.w;
            const int cgt1 = cgt2 + hh.z;
            const int cgt0 = cgt1 + hh.y;
            int pick = 0x7FFFFFFF;
            if (cgt3 < kk && kk <= cgt3 + hh.w) pick = ((4 * lane + 3) << 16) | (kk - cgt3);
            if (cgt2 < kk && kk <= cgt2 + hh.z) pick = ((4 * lane + 2) << 16) | (kk - cgt2);
            if (cgt1 < kk && kk <= cgt1 + hh.y) pick = ((4 * lane + 1) << 16) | (kk - cgt1);
            if (cgt0 < kk && kk <= cgt0 + hh.x) pick = ((4 * lane + 0) << 16) | (kk - cgt0);
            #pragma unroll
            for (int off = 32; off > 0; off >>= 1) pick = min(pick, __shfl_xor(pick, off));
            const unsigned digit = (unsigned)(pick >> 16);
            kk = pick & 0xFFFF;
            prefix |= digit << shift;
            pmask  |= 0xFFu << shift;
        }

        const unsigned short tu = (prefix & 0x8000u) ? (unsigned short)(prefix & 0x7FFFu)
                                                     : (unsigned short)((~prefix) & 0xFFFFu);
        const float thr = __half2float(__ushort_as_half(tu));

        float lg[16];
        float mx = -3.4e38f;
        #pragma unroll
        for (int i = 0; i < 16; ++i) {
            const float v = __half2float(__ushort_as_half(vs[i]));
            const float a = (v < thr) ? -1e-7f : v;
            lg[i] = a * (1.0f / 0.3f);
            mx = fmaxf(mx, lg[i]);
        }
        #pragma unroll
        for (int off = 32; off > 0; off >>= 1) mx = fmaxf(mx, __shfl_xor(mx, off));

        float e[16];
        float sum = 0.f;
        #pragma unroll
        for (int i = 0; i < 16; ++i) { e[i] = __expf(lg[i] - mx); sum += e[i]; }
        #pragma unroll
        for (int off = 32; off > 0; off >>= 1) sum += __shfl_xor(sum, off);
        const float inv = 1.0f / sum;

        unsigned short os[16];
        #pragma unroll
        for (int i = 0; i < 16; ++i) os[i] = __half_as_ushort(__float2half(e[i] * inv));
        *(uint4*)&P[base ^ key8]       = *(const uint4*)&os[0];
        *(uint4*)&P[(base + 8) ^ key8] = *(const uint4*)&os[8];
    }
    __syncthreads();

    // ---------------- Phase C: out = P @ hW_b + bias ----------------
    const int q4  = wave & 3;          // col quarter: 80 out-cols
    const int mi2 = (wave >> 2) & 1;   // row half: 16 rows
    const int kh  = wave >> 3;         // K half: 0 -> k<512, 1 -> k>=512

    f32x4 acc4[5];
    #pragma unroll
    for (int i = 0; i < 5; ++i) acc4[i] = (f32x4){0.f, 0.f, 0.f, 0.f};

    const __half* Wq = Wb + (long)(q4 * 80 + lrow) * 8192 + kh * 512 + quad * 8;
    const int rowA = mi2 * 16 + lrow;
    #pragma unroll
    for (int t = 0; t < 16; ++t) {
        half8 bh[5];
        #pragma unroll
        for (int cf = 0; cf < 5; ++cf)
            bh[cf] = *(const half8*)(Wq + (long)cf * 16 * 8192 + t * 32);
        const int kk = kh * 512 + t * 32 + quad * 8;
        const half8 ah = *(const half8*)&P[((rowA << 10) + kk) ^ ((rowA & 7) << 3)];
        #pragma unroll
        for (int cf = 0; cf < 5; ++cf)
            acc4[cf] = __builtin_amdgcn_mfma_f32_16x16x32_f16(
                ah, bh[cf], acc4[cf], 0, 0, 0);
    }

    __syncthreads();                 // all P reads done; P region now dead
    float* const red = (float*)P;    // 32 x 320 f32 = 40 KB, aliases P
    if (kh == 1) {
        #pragma unroll
        for (int cf = 0; cf < 5; ++cf)
            #pragma unroll
            for (int rr = 0; rr < 4; ++rr)
                red[(mi2 * 16 + quad * 4 + rr) * 320 + q4 * 80 + cf * 16 + lrow] =
                    acc4[cf][rr];
    }
    __syncthreads();
    if (kh == 0) {
        #pragma unroll
        for (int cf = 0; cf < 5; ++cf)
            #pragma unroll
            for (int rr = 0; rr < 4; ++rr) {
                const int row = mi2 * 16 + quad * 4 + rr;
                const int col = q4 * 80 + cf * 16 + lrow;
                out[(long)(b * 1024 + r0 + row) * 320 + col] =
                    acc4[cf][rr] + red[row * 320 + col] + bias[col];
            }
    }
}

extern "C" void kernel_launch(void* const* d_in, const int* in_sizes, int n_in,
                              void* d_out, int out_size, void* d_ws, size_t ws_size,
                              hipStream_t stream) {
    (void)in_sizes; (void)n_in; (void)out_size; (void)ws_size;

    const float* h      = (const float*)d_in[0];  // 8x1024x320
    const float* Wqk    = (const float*)d_in[1];  // 320x640
    const float* bqk    = (const float*)d_in[2];  // 640
    const float* weight = (const float*)d_in[3];  // 320x320
    const float* bias   = (const float*)d_in[4];  // 320
    float* out = (float*)d_out;                   // 8192x320

    // workspace layout
    char* p = (char*)d_ws;
    __half* h16  = (__half*)p; p += 2621440L * 2;        // 5 MB
    __half* Q    = (__half*)p; p += 2621440L * 2;        // 5 MB
    __half* Kb   = (__half*)p; p += 2621440L * 2;        // 5 MB
    __half* WqkT = (__half*)p; p += 640L * 320 * 2;      // 400 KB
    __half* wTp  = (__half*)p; p += 384L * 320 * 2;      // padded to 384 rows
    __half* hWT  = (__half*)p; p += 384L * 8192 * 2;     // 6 MB (incl pad rows)

    // --- prep (1 launch): h->fp16, WqkT, wTp ---
    prep_all<<<2860, 256, 0, stream>>>(h, (ushort4*)h16, Wqk, WqkT, weight, wTp);

    // --- combined: hWT (192 blocks) + G1' Q/K (320 blocks), BK=64 ---
    g1_combined<<<512, 256, 0, stream>>>(h16, wTp, WqkT, hWT, Q, Kb, bqk);

    // --- fused G2 + topk/softmax + G4: 16 waves/block, direct-L2 operands ---
    fused_attn<<<256, 1024, 0, stream>>>(Q, Kb, hWT, bias, out);
}

// Round 4
// 125.977 us; speedup vs baseline: 1.2974x; 1.2974x over previous
//
#include <hip/hip_runtime.h>
#include <hip/hip_fp16.h>

// ---------------------------------------------------------------------------
// B=8, N=1024, F=320, H=5 (heads collapse: at = (Q·K^T)/8)
// R19: fused_attn v4 — wave-autonomous staging, zero barriers in GEMM loops.
//   R17/R18 proved hipcc won't pipeline global->VGPR operand streams.
//   v4 returns to LDS staging (R16, best at 54.6us) but makes it WAVE-PRIVATE:
//   each wave stages only the operand rows it reads (its 128 at-cols of K,
//   its 80 out-cols of hW) into its own LDS dbuf via global_load_lds, and
//   synchronizes with per-wave counted `s_waitcnt vmcnt(N)` inline asm
//   (+sched_barrier(0)). No block barriers inside the K-loops -> no
//   all-wave vmcnt(0) drains (R16's ~50 barrier rounds were the stall).
//   5 block barriers total (phase boundaries only). hW chunk-0 prefetch is
//   issued before phase B so the B->C barrier drain is free.
//   LDS 152 KB: P 64K | S 88K region {Q 20K + Kbuf 8x8K | Wbuf 8x10K | red}
//   + hist 8K. 512 thr, grid 256, batch = bid&7 -> XCD L2 affinity.
//   Numerics: identical k-ascending chains + identical topk/softmax/reduce
//   as R16-R18 (all passed, absmax 0.03125) -> bit-identical.
// Pipeline: prep_all -> g1_combined (hWT + Q/K) -> fused_attn.
// ---------------------------------------------------------------------------

typedef __attribute__((ext_vector_type(8))) _Float16 half8;
typedef __attribute__((ext_vector_type(4))) float f32x4;

#define WAITV(N) do { asm volatile("s_waitcnt vmcnt(" #N ")" ::: "memory"); \
                      __builtin_amdgcn_sched_barrier(0); } while (0)

// ---- stage a (nrow16*16) x 32 fp16 tile into LDS, K-chunk XOR-swizzled -----
// (4-wave collective version, used by g1_combined only)
__device__ __forceinline__ void stage_tile(const __half* g, __half* lds,
                                           int nrow16, int ld, int wave, int lane) {
    const int r = lane >> 2;
    const int c = ((lane & 3) ^ ((lane >> 3) & 3)) * 8;  // swizzled chunk
    for (int i = wave; i < nrow16; i += 4) {
        const __half* src = g + (long)(i * 16 + r) * ld + c;
        __builtin_amdgcn_global_load_lds(
            (const __attribute__((address_space(1))) unsigned int*)src,
            (__attribute__((address_space(3))) unsigned int*)(lds + i * 512),
            16, 0, 0);
    }
}

// ---- wave-private stage: one wave stages nrow16*16 rows x 32 halfs --------
__device__ __forceinline__ void stage_wave(const __half* g, __half* lds,
                                           int nrow16, int ld, int lane) {
    const int r = lane >> 2;
    const int c = ((lane & 3) ^ ((lane >> 3) & 3)) * 8;  // swizzled chunk
    for (int i = 0; i < nrow16; ++i) {
        const __half* src = g + (long)(i * 16 + r) * ld + c;
        __builtin_amdgcn_global_load_lds(
            (const __attribute__((address_space(1))) unsigned int*)src,
            (__attribute__((address_space(3))) unsigned int*)(lds + i * 512),
            16, 0, 0);
    }
}

// ---------------------------------------------------------------------------
// 128x128 NT fp16 dbuf GEMM body, CH=2 (BK=64), runtime bx/by. K=320 -> 5
// barrier rounds. EPI 1: +bqk deinterleave -> Q,K. EPI 2: fp16 store (hWT).
// ---------------------------------------------------------------------------
template <int EPI>
__device__ __forceinline__ void gemm_body(
    const __half* __restrict__ A, const __half* __restrict__ B,
    void* __restrict__ C, void* __restrict__ C2, const float* __restrict__ bias,
    int lda, int ldb, int ldc, int bx, int by, __half* smem)
{
    constexpr int BUF = 16384;
    const int tid  = threadIdx.x;
    const int lane = tid & 63;
    const int wave = tid >> 6;
    const int wm   = wave >> 1;
    const int wn   = wave & 1;

    const __half* Ab = A + (long)by * 128 * lda;
    const __half* Bb = B + (long)bx * 128 * ldb;

    f32x4 acc[4][4];
    #pragma unroll
    for (int i = 0; i < 4; ++i)
        #pragma unroll
        for (int j = 0; j < 4; ++j) acc[i][j] = (f32x4){0.f, 0.f, 0.f, 0.f};

    const int lrow = lane & 15;
    const int quad = lane >> 4;
    const int swz = (quad ^ ((lrow >> 1) & 3)) * 8;

    #pragma unroll
    for (int c = 0; c < 2; ++c) {
        stage_tile(Ab + c * 32, smem + c * 4096, 8, lda, wave, lane);
        stage_tile(Bb + c * 32, smem + 8192 + c * 4096, 8, ldb, wave, lane);
    }

    for (int it = 0; it < 5; ++it) {
        __syncthreads();
        if (it + 1 < 5) {
            __half* nb = smem + ((it + 1) & 1) * BUF;
            const int k1 = (it + 1) * 64;
            #pragma unroll
            for (int c = 0; c < 2; ++c) {
                stage_tile(Ab + k1 + c * 32, nb + c * 4096, 8, lda, wave, lane);
                stage_tile(Bb + k1 + c * 32, nb + 8192 + c * 4096, 8, ldb, wave, lane);
            }
        }
        const __half* buf = smem + (it & 1) * BUF;
        #pragma unroll
        for (int c = 0; c < 2; ++c) {
            const __half* pA = buf + c * 4096 + (wm * 64 + lrow) * 32 + swz;
            const __half* pB = buf + 8192 + c * 4096 + (wn * 64 + lrow) * 32 + swz;
            half8 ah[4], bh[4];
            #pragma unroll
            for (int mt = 0; mt < 4; ++mt) ah[mt] = *(const half8*)(pA + mt * 512);
            #pragma unroll
            for (int nt = 0; nt < 4; ++nt) bh[nt] = *(const half8*)(pB + nt * 512);
            #pragma unroll
            for (int mt = 0; mt < 4; ++mt)
                #pragma unroll
                for (int nt = 0; nt < 4; ++nt)
                    acc[mt][nt] = __builtin_amdgcn_mfma_f32_16x16x32_f16(
                        ah[mt], bh[nt], acc[mt][nt], 0, 0, 0);
        }
    }

    const int row_base = by * 128 + wm * 64;
    const int col_base = bx * 128 + wn * 64;
    #pragma unroll
    for (int mt = 0; mt < 4; ++mt)
        #pragma unroll
        for (int nt = 0; nt < 4; ++nt)
            #pragma unroll
            for (int r = 0; r < 4; ++r) {
                const int row = row_base + mt * 16 + quad * 4 + r;
                const int col = col_base + nt * 16 + lrow;
                const float v = acc[mt][nt][r];
                if (EPI == 1) {
                    const float val = v + bias[col];
                    const long idx = (long)row * 320 + (col >> 1);
                    if (col & 1) ((__half*)C2)[idx] = __float2half(val);
                    else         ((__half*)C)[idx]  = __float2half(val);
                } else {
                    ((__half*)C)[(long)row * ldc + col] = __float2half(v);
                }
            }
}

// ---- combined: blocks 0..191 do hWT (64x3 tiles); 192..511 do G1' (5x64) ---
__global__ __launch_bounds__(256) void g1_combined(
    const __half* __restrict__ h16, const __half* __restrict__ wTp,
    const __half* __restrict__ WqkT, __half* __restrict__ hWT,
    __half* __restrict__ Q, __half* __restrict__ Kb,
    const float* __restrict__ bqk)
{
    __shared__ __half smem[2 * 16384];
    const int bx = blockIdx.x;
    if (bx < 192) {
        gemm_body<2>(wTp, h16, hWT, nullptr, nullptr,
                     320, 320, 8192, bx % 64, bx / 64, smem);
    } else {
        const int b = bx - 192;
        gemm_body<1>(h16, WqkT, Q, Kb, bqk,
                     320, 320, 320, b % 5, b / 5, smem);
    }
}

// ---- fused prep: h->fp16 (blocks 0..2559) | Wqk^T | weight^T --------------
__global__ __launch_bounds__(256) void prep_all(
    const float* __restrict__ h, ushort4* __restrict__ h16,
    const float* __restrict__ Wqk, __half* __restrict__ WqkT,
    const float* __restrict__ weight, __half* __restrict__ wTp)
{
    const int bx = blockIdx.x;
    if (bx < 2560) {
        const int i = bx * 256 + threadIdx.x;
        const float4 v = ((const float4*)h)[i];
        ushort4 o;
        o.x = __half_as_ushort(__float2half(v.x));
        o.y = __half_as_ushort(__float2half(v.y));
        o.z = __half_as_ushort(__float2half(v.z));
        o.w = __half_as_ushort(__float2half(v.w));
        h16[i] = o;
        return;
    }
    __shared__ float t[32][33];
    const float* src;
    __half* dst;
    int ldS, ldT, c0, r0;
    if (bx < 2760) {
        const int b = bx - 2560;
        src = Wqk; dst = WqkT; ldS = 640; ldT = 320;
        c0 = (b % 20) * 32; r0 = (b / 20) * 32;
    } else {
        const int b = bx - 2760;
        src = weight; dst = wTp; ldS = 320; ldT = 320;
        c0 = (b % 10) * 32; r0 = (b / 10) * 32;
    }
    const int lx = threadIdx.x & 31, ly = threadIdx.x >> 5;
    #pragma unroll
    for (int i = 0; i < 4; ++i)
        t[ly + 8 * i][lx] = src[(long)(r0 + ly + 8 * i) * ldS + c0 + lx];
    __syncthreads();
    #pragma unroll
    for (int i = 0; i < 4; ++i)
        dst[(long)(c0 + ly + 8 * i) * ldT + r0 + lx] = __float2half(t[lx][ly + 8 * i]);
}

// ---------------------------------------------------------------------------
// fused_attn v4: 512 thr (8 waves), grid 256 (1 block/CU), batch = bid&7.
// Phase A: P = 0.125 * Q @ K^T. Wave w owns at-cols [w*128, (w+1)*128) as
//   two 64-col groups; stages its own 64x32 K chunk into a wave-private
//   LDS dbuf (global_load_lds, counted vmcnt(4), no barriers). Q staged
//   once in LDS, block-XOR swizzled (conflict-free reads).
// Phase B: exact 171st-largest per row (2-pass radix, wave-private hist)
//   + softmax, in LDS; 4 rows/wave, no barriers inside.
// Phase C: out = attn @ hW_b + bias. Wave -> (q4 = w&3: 80 cols,
//   kh = w>>2: k-half); stages its own 80x32 hW chunk (vmcnt(5));
//   A-frags from P. f32 k-split reduction aliases P.
// ---------------------------------------------------------------------------
__global__ __launch_bounds__(512, 2) void fused_attn(
    const __half* __restrict__ Q, const __half* __restrict__ Kmat,
    const __half* __restrict__ hWT, const float* __restrict__ bias,
    float* __restrict__ out)
{
    __shared__ __half smem[77824];   // 155648 B
    __half* const P  = smem;         // 32768 halfs: 32x1024, idx ^= (row&7)<<3
    __half* const S  = smem + 32768; // 40960-half multiplex region
    __half* const QL = S;            // phase A: 10240 halfs (32x320, blk-swz)
    __half* const KB = S + 10240;    // phase A: 8 waves x 4096 halfs dbuf
    __half* const WB = S;            // phase C: 8 waves x 5120 halfs dbuf
    int (*const hist)[256] = (int(*)[256])(smem + 73728);  // 8 KB

    const int tid  = threadIdx.x;
    const int lane = tid & 63;
    const int wave = tid >> 6;       // 0..7
    const int lrow = lane & 15;
    const int quad = lane >> 4;
    const int swz  = (quad ^ ((lrow >> 1) & 3)) * 8;

    const int b  = blockIdx.x & 7;          // batch -> XCD affinity
    const int r0 = (blockIdx.x >> 3) * 32;  // query-row base

    const __half* Qb = Q    + (long)(b * 1024 + r0) * 320;
    const __half* Kb = Kmat + (long)b * 327680;
    const __half* Wb = hWT  + (long)b * 1024;

    // ---- stage Q (32x320) into QL, 8-half blocks XOR-swizzled by row&7 ----
    for (int i = wave; i < 20; i += 8) {
        const int s   = i * 64 + lane;       // slot 0..1279
        const int row = s / 40;
        const int cb  = s % 40;
        const int gb  = cb ^ (row & 7);      // global block held at this slot
        const __half* src = Qb + (long)row * 320 + gb * 8;
        __builtin_amdgcn_global_load_lds(
            (const __attribute__((address_space(1))) unsigned int*)src,
            (__attribute__((address_space(3))) unsigned int*)(QL + i * 512),
            16, 0, 0);
    }
    __half* const kb0 = KB + wave * 4096;    // this wave's K dbuf (2x2048)
    stage_wave(Kb + (long)(wave * 128) * 320, kb0, 4, 320, lane);  // r=0
    __syncthreads();   // barrier 1: Q + first K chunk visible

    // ---------------- Phase A: P = 0.125 * Q @ K^T ----------------
    #pragma unroll
    for (int cg = 0; cg < 2; ++cg) {
        f32x4 acc[4][2];
        #pragma unroll
        for (int i = 0; i < 4; ++i)
            #pragma unroll
            for (int j = 0; j < 2; ++j) acc[i][j] = (f32x4){0.f, 0.f, 0.f, 0.f};

        for (int kc = 0; kc < 10; ++kc) {
            const int r = cg * 10 + kc;
            if (r + 1 < 20) {
                const int cg1 = (r + 1) / 10, kc1 = (r + 1) % 10;
                stage_wave(Kb + (long)(wave * 128 + cg1 * 64) * 320 + kc1 * 32,
                           kb0 + ((r + 1) & 1) * 2048, 4, 320, lane);
                WAITV(4);          // chunk r landed; chunk r+1 in flight
            } else {
                WAITV(0);
            }
            const __half* kt = kb0 + (r & 1) * 2048;
            const int gbq = kc * 4 + quad;   // global 8-half block of Q
            half8 ah[2], bh[4];
            #pragma unroll
            for (int mi = 0; mi < 2; ++mi)
                ah[mi] = *(const half8*)&QL[(mi * 16 + lrow) * 320
                                            + (gbq ^ (lrow & 7)) * 8];
            #pragma unroll
            for (int cb = 0; cb < 4; ++cb)
                bh[cb] = *(const half8*)(kt + (cb * 16 + lrow) * 32 + swz);
            #pragma unroll
            for (int cb = 0; cb < 4; ++cb)
                #pragma unroll
                for (int mi = 0; mi < 2; ++mi)
                    acc[cb][mi] = __builtin_amdgcn_mfma_f32_16x16x32_f16(
                        ah[mi], bh[cb], acc[cb][mi], 0, 0, 0);
        }
        #pragma unroll
        for (int cb = 0; cb < 4; ++cb)
            #pragma unroll
            for (int mi = 0; mi < 2; ++mi)
                #pragma unroll
                for (int rr = 0; rr < 4; ++rr) {
                    const int row = mi * 16 + quad * 4 + rr;
                    const int col = wave * 128 + cg * 64 + cb * 16 + lrow;
                    P[((row << 10) + col) ^ ((row & 7) << 3)] =
                        __float2half(0.125f * acc[cb][mi][rr]);
                }
    }
    __syncthreads();   // barrier 2: P complete; KB/QL dead

    // ---- prefetch this wave's first hW chunk (lands during phase B) ----
    const int q4 = wave & 3;     // col quarter: 80 out-cols
    const int kh = wave >> 2;    // k-half
    __half* const wb0 = WB + wave * 5120;     // dbuf 2x2560
    const __half* Wbase = Wb + (long)(q4 * 80) * 8192 + kh * 512;
    stage_wave(Wbase, wb0, 5, 8192, lane);

    // ---------------- Phase B: topk + softmax (wave-private) ----------------
    #pragma unroll
    for (int j = 0; j < 4; ++j) {
        const int row  = wave * 4 + j;
        const int key8 = (row & 7) << 3;
        const int base = (row << 10) + lane * 16;

        unsigned short vs[16];
        *(uint4*)&vs[0] = *(const uint4*)&P[base ^ key8];
        *(uint4*)&vs[8] = *(const uint4*)&P[(base + 8) ^ key8];

        unsigned key[16];
        #pragma unroll
        for (int i = 0; i < 16; ++i) {
            const unsigned u = vs[i];
            key[i] = (u & 0x8000u) ? ((~u) & 0xFFFFu) : (u | 0x8000u);
        }

        unsigned prefix = 0, pmask = 0;
        int kk = 171;

        #pragma unroll
        for (int pass = 0; pass < 2; ++pass) {
            const int shift = 8 - 8 * pass;
            *(int4*)&hist[wave][lane * 4] = make_int4(0, 0, 0, 0);
            #pragma unroll
            for (int i = 0; i < 16; ++i) {
                if ((key[i] & pmask) == prefix)
                    atomicAdd(&hist[wave][(key[i] >> shift) & 255], 1);
            }
            const int4 hh = *(const int4*)&hist[wave][lane * 4];
            const int s = hh.x + hh.y + hh.z + hh.w;
            int suf = s;
            #pragma unroll
            for (int off = 1; off < 64; off <<= 1) {
                const int o = __shfl_down(suf, off);
                if (lane + off < 64) suf += o;
            }
            const int cgt3 = suf - s;
            const int cgt2 = cgt3 + hh.w;
            const int cgt1 = cgt2 + hh.z;
            const int cgt0 = cgt1 + hh.y;
            int pick = 0x7FFFFFFF;
            if (cgt3 < kk && kk <= cgt3 + hh.w) pick = ((4 * lane + 3) << 16) | (kk - cgt3);
            if (cgt2 < kk && kk <= cgt2 + hh.z) pick = ((4 * lane + 2) << 16) | (kk - cgt2);
            if (cgt1 < kk && kk <= cgt1 + hh.y) pick = ((4 * lane + 1) << 16) | (kk - cgt1);
            if (cgt0 < kk && kk <= cgt0 + hh.x) pick = ((4 * lane + 0) << 16) | (kk - cgt0);
            #pragma unroll
            for (int off = 32; off > 0; off >>= 1) pick = min(pick, __shfl_xor(pick, off));
            const unsigned digit = (unsigned)(pick >> 16);
            kk = pick & 0xFFFF;
            prefix |= digit << shift;
            pmask  |= 0xFFu << shift;
        }

        const unsigned short tu = (prefix & 0x8000u) ? (unsigned short)(prefix & 0x7FFFu)
                                                     : (unsigned short)((~prefix) & 0xFFFFu);
        const float thr = __half2float(__ushort_as_half(tu));

        float lg[16];
        float mx = -3.4e38f;
        #pragma unroll
        for (int i = 0; i < 16; ++i) {
            const float v = __half2float(__ushort_as_half(vs[i]));
            const float a = (v < thr) ? -1e-7f : v;
            lg[i] = a * (1.0f / 0.3f);
            mx = fmaxf(mx, lg[i]);
        }
        #pragma unroll
        for (int off = 32; off > 0; off >>= 1) mx = fmaxf(mx, __shfl_xor(mx, off));

        float e[16];
        float sum = 0.f;
        #pragma unroll
        for (int i = 0; i < 16; ++i) { e[i] = __expf(lg[i] - mx); sum += e[i]; }
        #pragma unroll
        for (int off = 32; off > 0; off >>= 1) sum += __shfl_xor(sum, off);
        const float inv = 1.0f / sum;

        unsigned short os[16];
        #pragma unroll
        for (int i = 0; i < 16; ++i) os[i] = __half_as_ushort(__float2half(e[i] * inv));
        *(uint4*)&P[base ^ key8]       = *(const uint4*)&os[0];
        *(uint4*)&P[(base + 8) ^ key8] = *(const uint4*)&os[8];
    }
    __syncthreads();   // barrier 3: attn in P; W chunk 0 already landed

    // ---------------- Phase C: out = P @ hW_b + bias ----------------
    f32x4 acc4[5][2];
    #pragma unroll
    for (int i = 0; i < 5; ++i)
        #pragma unroll
        for (int j = 0; j < 2; ++j) acc4[i][j] = (f32x4){0.f, 0.f, 0.f, 0.f};

    for (int t = 0; t < 16; ++t) {
        if (t + 1 < 16) {
            stage_wave(Wbase + (t + 1) * 32, wb0 + ((t + 1) & 1) * 2560,
                       5, 8192, lane);
            WAITV(5);          // chunk t landed; chunk t+1 in flight
        } else {
            WAITV(0);
        }
        const __half* T = wb0 + (t & 1) * 2560;
        const int kk = kh * 512 + t * 32 + quad * 8;
        half8 ah[2], bh[5];
        #pragma unroll
        for (int mi = 0; mi < 2; ++mi) {
            const int row = mi * 16 + lrow;
            ah[mi] = *(const half8*)&P[((row << 10) + kk) ^ ((row & 7) << 3)];
        }
        #pragma unroll
        for (int cf = 0; cf < 5; ++cf)
            bh[cf] = *(const half8*)(T + (cf * 16 + lrow) * 32 + swz);
        #pragma unroll
        for (int cf = 0; cf < 5; ++cf)
            #pragma unroll
            for (int mi = 0; mi < 2; ++mi)
                acc4[cf][mi] = __builtin_amdgcn_mfma_f32_16x16x32_f16(
                    ah[mi], bh[cf], acc4[cf][mi], 0, 0, 0);
    }

    __syncthreads();   // barrier 4: all P reads done; P region now dead
    float* const red = (float*)P;    // 32 x 320 f32 = 40 KB, aliases P
    if (kh == 1) {
        #pragma unroll
        for (int cf = 0; cf < 5; ++cf)
            #pragma unroll
            for (int mi = 0; mi < 2; ++mi)
                #pragma unroll
                for (int rr = 0; rr < 4; ++rr)
                    red[(mi * 16 + quad * 4 + rr) * 320 + q4 * 80 + cf * 16 + lrow] =
                        acc4[cf][mi][rr];
    }
    __syncthreads();   // barrier 5
    if (kh == 0) {
        #pragma unroll
        for (int cf = 0; cf < 5; ++cf)
            #pragma unroll
            for (int mi = 0; mi < 2; ++mi)
                #pragma unroll
                for (int rr = 0; rr < 4; ++rr) {
                    const int row = mi * 16 + quad * 4 + rr;
                    const int col = q4 * 80 + cf * 16 + lrow;
                    out[(long)(b * 1024 + r0 + row) * 320 + col] =
                        acc4[cf][mi][rr] + red[row * 320 + col] + bias[col];
                }
    }
}

extern "C" void kernel_launch(void* const* d_in, const int* in_sizes, int n_in,
                              void* d_out, int out_size, void* d_ws, size_t ws_size,
                              hipStream_t stream) {
    (void)in_sizes; (void)n_in; (void)out_size; (void)ws_size;

    const float* h      = (const float*)d_in[0];  // 8x1024x320
    const float* Wqk    = (const float*)d_in[1];  // 320x640
    const float* bqk    = (const float*)d_in[2];  // 640
    const float* weight = (const float*)d_in[3];  // 320x320
    const float* bias   = (const float*)d_in[4];  // 320
    float* out = (float*)d_out;                   // 8192x320

    // workspace layout
    char* p = (char*)d_ws;
    __half* h16  = (__half*)p; p += 2621440L * 2;        // 5 MB
    __half* Q    = (__half*)p; p += 2621440L * 2;        // 5 MB
    __half* Kb   = (__half*)p; p += 2621440L * 2;        // 5 MB
    __half* WqkT = (__half*)p; p += 640L * 320 * 2;      // 400 KB
    __half* wTp  = (__half*)p; p += 384L * 320 * 2;      // padded to 384 rows
    __half* hWT  = (__half*)p; p += 384L * 8192 * 2;     // 6 MB (incl pad rows)

    // --- prep (1 launch): h->fp16, WqkT, wTp ---
    prep_all<<<2860, 256, 0, stream>>>(h, (ushort4*)h16, Wqk, WqkT, weight, wTp);

    // --- combined: hWT (192 blocks) + G1' Q/K (320 blocks), BK=64 ---
    g1_combined<<<512, 256, 0, stream>>>(h16, wTp, WqkT, hWT, Q, Kb, bqk);

    // --- fused G2 + topk/softmax + G4: wave-autonomous staging ---
    fused_attn<<<256, 512, 0, stream>>>(Q, Kb, hWT, bias, out);
}